// Round 10
// baseline (1115.999 us; speedup 1.0000x reference)
//
#include <hip/hip_runtime.h>
#include <hip/hip_fp16.h>

// SiameseBrainNet: 3-layer GCN encoder (shared weights) x2 + mean-pool + pairwise distance.
// D = H = 512 hard-coded. Encoders fused along M (concat A|B). GEMMs: split-bf16 (hi/lo)
// 3-MFMA fp32 emulation, 2-phase double-buffered LDS (T3 minimum recipe); fp16 H plane
// for the gather-bound aggregation (measured ~4 TB/s pattern ceiling, volume-bound).

typedef short bf16x8 __attribute__((ext_vector_type(8)));
typedef float f32x4 __attribute__((ext_vector_type(4)));

__device__ __forceinline__ unsigned short f2bf(float f) {
    union { float f; unsigned u; } v; v.f = f;
    unsigned r = (v.u + 0x7fffu + ((v.u >> 16) & 1u)) >> 16;  // RNE
    return (unsigned short)r;
}
__device__ __forceinline__ float bf2f(unsigned short h) {
    union { unsigned u; float f; } v; v.u = ((unsigned)h) << 16;
    return v.f;
}

__device__ __forceinline__ void gload16(const unsigned short* g, unsigned short* lds) {
    __builtin_amdgcn_global_load_lds(
        (const __attribute__((address_space(1))) unsigned int*)g,
        (__attribute__((address_space(3))) unsigned int*)lds, 16, 0, 0);
}

// ---------------- CSR build (both encoders per dispatch) ----------------

__global__ __launch_bounds__(256) void deg2_kernel(const int* __restrict__ ei_a,
                                                   const int* __restrict__ ei_b,
                                                   int* __restrict__ deg,  // [2N]
                                                   int n, int e) {
    int i = blockIdx.x * 256 + threadIdx.x;
    if (i >= 2 * e) return;
    if (i < e) {
        atomicAdd(&deg[ei_a[e + i]], 1);
    } else {
        atomicAdd(&deg[n + ei_b[e + (i - e)]], 1);
    }
}

// scan + dinv fused; grid = 2 (one block per encoder).
__global__ __launch_bounds__(1024) void scan2_kernel(const int* __restrict__ deg_all,
                                                     int* __restrict__ rp_all,
                                                     int* __restrict__ cur_all,
                                                     float* __restrict__ dinv_all, int n) {
    int enc = blockIdx.x;
    const int* deg = deg_all + (size_t)enc * n;
    int* row_ptr = rp_all + (size_t)enc * (n + 1);
    int* cursor = cur_all + (size_t)enc * n;
    float* dinv = dinv_all + (size_t)enc * n;

    __shared__ int sums[1024];
    int t = threadIdx.x;
    int chunk = (n + 1023) >> 10;
    int beg = t * chunk;
    int end = beg + chunk;
    if (beg > n) beg = n;
    if (end > n) end = n;
    int s = 0;
    for (int i = beg; i < end; ++i) s += deg[i];
    sums[t] = s;
    __syncthreads();
    for (int off = 1; off < 1024; off <<= 1) {
        int v = (t >= off) ? sums[t - off] : 0;
        __syncthreads();
        sums[t] += v;
        __syncthreads();
    }
    int run = sums[t] - s;
    for (int i = beg; i < end; ++i) {
        row_ptr[i] = run;
        cursor[i] = run;
        dinv[i] = rsqrtf((float)deg[i] + 1.0f);  // self-loop: deg+1
        run += deg[i];
    }
    if (t == 1023) row_ptr[n] = sums[1023];
}

// packed edge: {src, norm}; both encoders per dispatch
__global__ __launch_bounds__(256) void fill2_kernel(const int* __restrict__ ei_a,
                                                    const int* __restrict__ ei_b,
                                                    const float* __restrict__ dinv_all,
                                                    int* __restrict__ cur_all,
                                                    int2* __restrict__ ed_all,
                                                    int n, int e) {
    int i = blockIdx.x * 256 + threadIdx.x;
    if (i >= 2 * e) return;
    int enc = (i >= e) ? 1 : 0;
    int j = i - enc * e;
    const int* ei = enc ? ei_b : ei_a;
    const float* dinv = dinv_all + (size_t)enc * n;
    int* cursor = cur_all + (size_t)enc * n;
    int2* edges = ed_all + (size_t)enc * e;
    int s = ei[j], d = ei[e + j];
    int p = atomicAdd(&cursor[d], 1);
    int2 pr;
    pr.x = s;
    pr.y = __float_as_int(dinv[s] * dinv[d]);
    edges[p] = pr;
}

// ---------------- graph ranges from sorted batch (both encoders) ----------------

__global__ __launch_bounds__(256) void ranges2_kernel(const int* __restrict__ batch_a,
                                                      const int* __restrict__ batch_b,
                                                      int* __restrict__ startA,
                                                      int* __restrict__ startB,
                                                      int n, int g) {
    int i = blockIdx.x * 256 + threadIdx.x;
    if (i >= 2 * n) return;
    int enc = (i >= n) ? 1 : 0;
    int j = i - enc * n;
    const int* batch = enc ? batch_b : batch_a;
    int* start = enc ? startB : startA;
    int b = batch[j];
    if (j == 0) {
        for (int k = 0; k <= b; ++k) start[k] = 0;
    } else {
        int pb = batch[j - 1];
        for (int k = pb + 1; k <= b; ++k) start[k] = j;
    }
    if (j == n - 1) {
        for (int k = b + 1; k <= g; ++k) start[k] = n;
    }
}

// ---------------- W pre-transpose + bf16 hi/lo split (all 3 layers, one dispatch) ----------------

__global__ __launch_bounds__(256) void wsplit3_kernel(const float* __restrict__ W1,
                                                      const float* __restrict__ W2,
                                                      const float* __restrict__ W3,
                                                      unsigned short* __restrict__ hi_all,
                                                      unsigned short* __restrict__ lo_all) {
    __shared__ float tile[32][33];
    int layer = blockIdx.x >> 8;
    int b = blockIdx.x & 255;
    const float* W = (layer == 0) ? W1 : (layer == 1) ? W2 : W3;
    unsigned short* Wt_hi = hi_all + (size_t)layer * 512 * 512;
    unsigned short* Wt_lo = lo_all + (size_t)layer * 512 * 512;
    int k0 = (b & 15) * 32, n0 = (b >> 4) * 32;
    int t = threadIdx.x;
    int tc = t & 31, tr = t >> 5;
#pragma unroll
    for (int it = 0; it < 4; ++it)
        tile[tr + it * 8][tc] = W[(size_t)(k0 + tr + it * 8) * 512 + n0 + tc];
    __syncthreads();
#pragma unroll
    for (int it = 0; it < 4; ++it) {
        int n = tr + it * 8;
        float v = tile[tc][n];
        unsigned short hi = f2bf(v);
        unsigned short lo = f2bf(v - bf2f(hi));
        Wt_hi[(size_t)(n0 + n) * 512 + k0 + tc] = hi;
        Wt_lo[(size_t)(n0 + n) * 512 + k0 + tc] = lo;
    }
}

// ---------------- A bf16 hi/lo split (layer-1 input, both encoders) ----------------

__global__ __launch_bounds__(256) void asplit2_kernel(const float* __restrict__ x_a,
                                                      const float* __restrict__ x_b,
                                                      unsigned short* __restrict__ A_hi,
                                                      unsigned short* __restrict__ A_lo,
                                                      int n4) {
    int i = blockIdx.x * 256 + threadIdx.x;
    if (i >= 2 * n4) return;
    float4 v = (i < n4) ? ((const float4*)x_a)[i] : ((const float4*)x_b)[i - n4];
    ushort4 h, l;
    h.x = f2bf(v.x); l.x = f2bf(v.x - bf2f(h.x));
    h.y = f2bf(v.y); l.y = f2bf(v.y - bf2f(h.y));
    h.z = f2bf(v.z); l.z = f2bf(v.z - bf2f(h.z));
    h.w = f2bf(v.w); l.w = f2bf(v.w - bf2f(h.w));
    ((ushort4*)A_hi)[i] = h;
    ((ushort4*)A_lo)[i] = l;
}

// ---------------- split-bf16 MFMA GEMM: C16[M x 512] = A[M x 512] @ W[512 x 512] ----------------
// BM=128 BN=128 BK=32, 256 threads (4 waves, 2x2), per-wave 64x64 via 4x4 frags of 16x16x32.
// 2-phase double-buffered: STAGE(t+1) issued before compute(t); one __syncthreads per K-step
// (drains vmcnt for the prefetch AND fences buffer reuse). LDS 64 KB -> 2 blocks/CU.

__global__ __launch_bounds__(256, 2) void gemm_mfma_kernel(const unsigned short* __restrict__ A_hi,
                                                           const unsigned short* __restrict__ A_lo,
                                                           const unsigned short* __restrict__ Bt_hi,
                                                           const unsigned short* __restrict__ Bt_lo,
                                                           __half* __restrict__ C, int M) {
    __shared__ unsigned short As_hi[2][128][32], As_lo[2][128][32];
    __shared__ unsigned short Bs_hi[2][128][32], Bs_lo[2][128][32];
    int nb = blockIdx.x & 3;
    int mb = blockIdx.x >> 2;
    int row0 = mb * 128, col0 = nb * 128;
    int t = threadIdx.x;
    int lane = t & 63, w = t >> 6;
    int wm = w >> 1, wn = w & 1;
    int r = lane & 15, g = lane >> 4;

    f32x4 acc[4][4] = {};

    int r4 = t >> 2;          // 0..63: row within half-tile
    int kq = (t & 3) * 8;     // k-quarter (elements)

    auto STAGE = [&](int buf, int k0) {
#pragma unroll
        for (int i = 0; i < 2; ++i) {
            int ldsrow = i * 64 + w * 16;
            gload16(A_hi + (size_t)(row0 + i * 64 + r4) * 512 + k0 + kq, &As_hi[buf][ldsrow][0]);
            gload16(A_lo + (size_t)(row0 + i * 64 + r4) * 512 + k0 + kq, &As_lo[buf][ldsrow][0]);
            gload16(Bt_hi + (size_t)(col0 + i * 64 + r4) * 512 + k0 + kq, &Bs_hi[buf][ldsrow][0]);
            gload16(Bt_lo + (size_t)(col0 + i * 64 + r4) * 512 + k0 + kq, &Bs_lo[buf][ldsrow][0]);
        }
    };

    STAGE(0, 0);
    __syncthreads();  // vmcnt(0)+lgkm+barrier: tile 0 resident

    int cur = 0;
    for (int ks = 0; ks < 16; ++ks) {
        if (ks < 15) STAGE(cur ^ 1, (ks + 1) * 32);  // prefetch next tile (stays in flight)

        bf16x8 ah[4], al[4], bh[4], bl[4];
#pragma unroll
        for (int m = 0; m < 4; ++m) {
            int rr = wm * 64 + m * 16 + r;
            ah[m] = *(const bf16x8*)&As_hi[cur][rr][g * 8];
            al[m] = *(const bf16x8*)&As_lo[cur][rr][g * 8];
        }
#pragma unroll
        for (int n = 0; n < 4; ++n) {
            int cc = wn * 64 + n * 16 + r;
            bh[n] = *(const bf16x8*)&Bs_hi[cur][cc][g * 8];
            bl[n] = *(const bf16x8*)&Bs_lo[cur][cc][g * 8];
        }
#pragma unroll
        for (int m = 0; m < 4; ++m)
#pragma unroll
            for (int n = 0; n < 4; ++n) {
                acc[m][n] = __builtin_amdgcn_mfma_f32_16x16x32_bf16(al[m], bh[n], acc[m][n], 0, 0, 0);
                acc[m][n] = __builtin_amdgcn_mfma_f32_16x16x32_bf16(ah[m], bl[n], acc[m][n], 0, 0, 0);
                acc[m][n] = __builtin_amdgcn_mfma_f32_16x16x32_bf16(ah[m], bh[n], acc[m][n], 0, 0, 0);
            }
        __syncthreads();  // prefetch landed + all waves done reading cur
        cur ^= 1;
    }

#pragma unroll
    for (int m = 0; m < 4; ++m)
#pragma unroll
        for (int j = 0; j < 4; ++j) {
            int rr = row0 + wm * 64 + m * 16 + g * 4 + j;
            if (rr < M) {
#pragma unroll
                for (int n = 0; n < 4; ++n)
                    C[(size_t)rr * 512 + col0 + wn * 64 + n * 16 + r] =
                        __float2half(acc[m][n][j]);
            }
        }
}

// ---------------- fused aggregation (both encoders): one block per dst node ----------------
// agg[d] = sum_{e: dst=d} h16[src]*norm + h16[d]*dinv[d]^2 + b ; optional relu;
// output either bf16 hi/lo (next GEMM input) or fp32 (pool input).

template <bool RELU, bool SPLIT>
__global__ __launch_bounds__(256) void aggregate_kernel(const __half* __restrict__ H,  // [2N][512]
                                                        const int* __restrict__ rp_all,
                                                        const int2* __restrict__ ed_all,
                                                        const float* __restrict__ dinv_all,
                                                        const float* __restrict__ bias,
                                                        float* __restrict__ X,
                                                        unsigned short* __restrict__ Xhi,
                                                        unsigned short* __restrict__ Xlo,
                                                        int n, int e) {
    int dg = blockIdx.x;           // global row (concat)
    bool isB = dg >= n;
    int d = isB ? dg - n : dg;     // local node id
    const int* rp = rp_all + (isB ? (size_t)(n + 1) : 0);
    const int2* ed = ed_all + (isB ? (size_t)e : 0);
    const float* dv = dinv_all + (isB ? (size_t)n : 0);
    const __half* Hb = H + (isB ? (size_t)n * 512 : 0);

    int t = threadIdx.x;
    int beg = rp[d], end = rp[d + 1];
    float ax = 0.f, ay = 0.f;
    int j = beg;
    for (; j + 4 <= end; j += 4) {
        int2 e0 = ed[j], e1 = ed[j + 1], e2 = ed[j + 2], e3 = ed[j + 3];
        __half2 h0 = *(const __half2*)(Hb + (size_t)e0.x * 512 + t * 2);
        __half2 h1 = *(const __half2*)(Hb + (size_t)e1.x * 512 + t * 2);
        __half2 h2 = *(const __half2*)(Hb + (size_t)e2.x * 512 + t * 2);
        __half2 h3 = *(const __half2*)(Hb + (size_t)e3.x * 512 + t * 2);
        float2 f0 = __half22float2(h0), f1 = __half22float2(h1);
        float2 f2 = __half22float2(h2), f3 = __half22float2(h3);
        float w0 = __int_as_float(e0.y), w1 = __int_as_float(e1.y);
        float w2 = __int_as_float(e2.y), w3 = __int_as_float(e3.y);
        ax += w0 * f0.x + w1 * f1.x + w2 * f2.x + w3 * f3.x;
        ay += w0 * f0.y + w1 * f1.y + w2 * f2.y + w3 * f3.y;
    }
    for (; j < end; ++j) {
        int2 ej = ed[j];
        float w = __int_as_float(ej.y);
        float2 f = __half22float2(*(const __half2*)(Hb + (size_t)ej.x * 512 + t * 2));
        ax += w * f.x;
        ay += w * f.y;
    }
    float di = dv[d];
    float self = di * di;
    float2 hd = __half22float2(*(const __half2*)(Hb + (size_t)d * 512 + t * 2));
    float2 bb = *(const float2*)(bias + t * 2);
    float ox = ax + self * hd.x + bb.x;
    float oy = ay + self * hd.y + bb.y;
    if (RELU) {
        ox = fmaxf(ox, 0.f);
        oy = fmaxf(oy, 0.f);
    }
    if (SPLIT) {
        unsigned short hx = f2bf(ox), hy = f2bf(oy);
        unsigned short lx = f2bf(ox - bf2f(hx)), ly = f2bf(oy - bf2f(hy));
        *(ushort2*)(Xhi + (size_t)dg * 512 + t * 2) = make_ushort2(hx, hy);
        *(ushort2*)(Xlo + (size_t)dg * 512 + t * 2) = make_ushort2(lx, ly);
    } else {
        *(float2*)(X + (size_t)dg * 512 + t * 2) = make_float2(ox, oy);
    }
}

// ---------------- mean pool over sorted-batch ranges (both encoders) ----------------

__global__ __launch_bounds__(256) void pool_kernel(const float* __restrict__ X,  // [2N][512]
                                                   const int* __restrict__ startA,
                                                   const int* __restrict__ startB,
                                                   float* __restrict__ pool,  // [2G][512]
                                                   int n, int gcount) {
    int g = blockIdx.x;
    bool isB = g >= gcount;
    const int* st = isB ? startB : startA;
    int gl = isB ? g - gcount : g;
    const float* Xb = X + (isB ? (size_t)n * 512 : 0);
    int t = threadIdx.x;
    int s = st[gl], e = st[gl + 1];
    float ax = 0.f, ay = 0.f;
    int i = s;
    for (; i + 2 <= e; i += 2) {
        float2 v0 = *(const float2*)(Xb + (size_t)i * 512 + t * 2);
        float2 v1 = *(const float2*)(Xb + (size_t)(i + 1) * 512 + t * 2);
        ax += v0.x + v1.x;
        ay += v0.y + v1.y;
    }
    for (; i < e; ++i) {
        float2 v = *(const float2*)(Xb + (size_t)i * 512 + t * 2);
        ax += v.x;
        ay += v.y;
    }
    float cnt = fmaxf((float)(e - s), 1.0f);
    *(float2*)(pool + (size_t)g * 512 + t * 2) = make_float2(ax / cnt, ay / cnt);
}

// ---------------- pairwise distance ----------------

__global__ __launch_bounds__(64) void pdist_kernel(const float* __restrict__ pool,
                                                   float* __restrict__ out, int gcount) {
    int g = blockIdx.x;
    int t = threadIdx.x;
    const float* pa = pool + (size_t)g * 512;
    const float* pb = pool + (size_t)(gcount + g) * 512;
    float s = 0.f;
    for (int i = t; i < 512; i += 64) {
        float d = pa[i] - pb[i] + 1e-6f;
        s += d * d;
    }
#pragma unroll
    for (int off = 32; off; off >>= 1) s += __shfl_down(s, off);
    if (t == 0) out[g] = sqrtf(s);
}

// ---------------- launch ----------------

extern "C" void kernel_launch(void* const* d_in, const int* in_sizes, int n_in,
                              void* d_out, int out_size, void* d_ws, size_t ws_size,
                              hipStream_t stream) {
    const float* x_a = (const float*)d_in[0];
    const int* ei_a = (const int*)d_in[1];
    const int* batch_a = (const int*)d_in[2];
    const float* x_b = (const float*)d_in[3];
    const int* ei_b = (const int*)d_in[4];
    const int* batch_b = (const int*)d_in[5];
    const float* W1 = (const float*)d_in[6];
    const float* b1 = (const float*)d_in[7];
    const float* W2 = (const float*)d_in[8];
    const float* b2 = (const float*)d_in[9];
    const float* W3 = (const float*)d_in[10];
    const float* b3 = (const float*)d_in[11];
    float* out = (float*)d_out;

    const int N = in_sizes[0] / 512;
    const int E = in_sizes[1] / 2;
    const int G = out_size;
    const int M = 2 * N;                      // concat A|B
    const int Mpad = ((M + 127) / 128) * 128; // GEMM tail rows read junk, never stored

    char* ws = (char*)d_ws;
    size_t off = 0;
    auto alloc = [&](size_t bytes) -> void* {
        void* p = ws + off;
        off = (off + bytes + 255) & ~(size_t)255;
        return p;
    };
    __half* bufH16 = (__half*)alloc((size_t)Mpad * 512 * 2);
    // a_hi | a_lo block; also aliased as fp32 X for layer-3 output (a_hi/a_lo dead by then)
    char* abblock = (char*)alloc((size_t)Mpad * 512 * 4);
    unsigned short* a_hi = (unsigned short*)abblock;
    unsigned short* a_lo = a_hi + (size_t)Mpad * 512;
    float* bufX = (float*)abblock;
    int* deg = (int*)alloc((size_t)2 * N * 4);        // [A | B]
    float* dinv = (float*)alloc((size_t)2 * N * 4);   // [A | B]
    int* rp = (int*)alloc((size_t)2 * (N + 1) * 4);   // [A | B]
    int* cur = (int*)alloc((size_t)2 * N * 4);        // [A | B]
    int2* ed = (int2*)alloc((size_t)2 * E * 8);       // [A | B]
    int* startA = (int*)alloc((size_t)(G + 1) * 4);
    int* startB = (int*)alloc((size_t)(G + 1) * 4);
    float* pool = (float*)alloc((size_t)2 * G * 512 * 4);
    unsigned short* wt_hi = (unsigned short*)alloc((size_t)3 * 512 * 512 * 2);
    unsigned short* wt_lo = (unsigned short*)alloc((size_t)3 * 512 * 512 * 2);

    const int gemm_grid = 4 * (Mpad / 128);
    const int n4 = N * 512 / 4;

    // weights: pre-transpose + split, all 3 layers (same every call; graph-capture safe)
    wsplit3_kernel<<<768, 256, 0, stream>>>(W1, W2, W3, wt_hi, wt_lo);

    // CSR build (A and B fused per dispatch), batch ranges
    hipMemsetAsync(deg, 0, (size_t)2 * N * 4, stream);
    deg2_kernel<<<(2 * E + 255) / 256, 256, 0, stream>>>(ei_a, ei_b, deg, N, E);
    scan2_kernel<<<2, 1024, 0, stream>>>(deg, rp, cur, dinv, N);
    fill2_kernel<<<(2 * E + 255) / 256, 256, 0, stream>>>(ei_a, ei_b, dinv, cur, ed, N, E);
    ranges2_kernel<<<(2 * N + 255) / 256, 256, 0, stream>>>(batch_a, batch_b, startA, startB, N, G);

    // layer-1 input: split x_a|x_b into concat bf16 hi/lo
    asplit2_kernel<<<(2 * n4 + 255) / 256, 256, 0, stream>>>(x_a, x_b, a_hi, a_lo, n4);

    // layer 1
    gemm_mfma_kernel<<<gemm_grid, 256, 0, stream>>>(a_hi, a_lo, wt_hi, wt_lo, bufH16, M);
    aggregate_kernel<true, true><<<M, 256, 0, stream>>>(bufH16, rp, ed, dinv, b1,
                                                        bufX, a_hi, a_lo, N, E);
    // layer 2
    gemm_mfma_kernel<<<gemm_grid, 256, 0, stream>>>(a_hi, a_lo, wt_hi + (size_t)512 * 512,
                                                    wt_lo + (size_t)512 * 512, bufH16, M);
    aggregate_kernel<true, true><<<M, 256, 0, stream>>>(bufH16, rp, ed, dinv, b2,
                                                        bufX, a_hi, a_lo, N, E);
    // layer 3 (fp32 out into the dead a_hi/a_lo block)
    gemm_mfma_kernel<<<gemm_grid, 256, 0, stream>>>(a_hi, a_lo, wt_hi + (size_t)2 * 512 * 512,
                                                    wt_lo + (size_t)2 * 512 * 512, bufH16, M);
    aggregate_kernel<false, false><<<M, 256, 0, stream>>>(bufH16, rp, ed, dinv, b3,
                                                          bufX, a_hi, a_lo, N, E);

    // pool + distance
    pool_kernel<<<2 * G, 256, 0, stream>>>(bufX, startA, startB, pool, N, G);
    pdist_kernel<<<G, 64, 0, stream>>>(pool, out, G);
}

// Round 13
// 1099.204 us; speedup vs baseline: 1.0153x; 1.0153x over previous
//
#include <hip/hip_runtime.h>
#include <hip/hip_fp16.h>

// SiameseBrainNet: 3-layer GCN encoder (shared weights) x2 + mean-pool + pairwise distance.
// D = H = 512 hard-coded. Encoders fused along M (concat A|B). GEMMs: split-bf16 (hi/lo)
// 3-MFMA fp32 emulation. GEMM tiling BM=64 x BN=512 (full width): A-plane read ONCE per
// GEMM (was 4x with BN=128 -> 328 MB through the ~4 TB/s L2-miss path = the measured
// ~165 us/GEMM). fp16 H plane for the gather-bound aggregation (~4 TB/s pattern ceiling).

typedef short bf16x8 __attribute__((ext_vector_type(8)));
typedef float f32x4 __attribute__((ext_vector_type(4)));

__device__ __forceinline__ unsigned short f2bf(float f) {
    union { float f; unsigned u; } v; v.f = f;
    unsigned r = (v.u + 0x7fffu + ((v.u >> 16) & 1u)) >> 16;  // RNE
    return (unsigned short)r;
}
__device__ __forceinline__ float bf2f(unsigned short h) {
    union { unsigned u; float f; } v; v.u = ((unsigned)h) << 16;
    return v.f;
}

__device__ __forceinline__ void gload16(const unsigned short* g, unsigned short* lds) {
    __builtin_amdgcn_global_load_lds(
        (const __attribute__((address_space(1))) unsigned int*)g,
        (__attribute__((address_space(3))) unsigned int*)lds, 16, 0, 0);
}

// ---------------- CSR build (both encoders per dispatch) ----------------

__global__ __launch_bounds__(256) void deg2_kernel(const int* __restrict__ ei_a,
                                                   const int* __restrict__ ei_b,
                                                   int* __restrict__ deg,  // [2N]
                                                   int n, int e) {
    int i = blockIdx.x * 256 + threadIdx.x;
    if (i >= 2 * e) return;
    if (i < e) {
        atomicAdd(&deg[ei_a[e + i]], 1);
    } else {
        atomicAdd(&deg[n + ei_b[e + (i - e)]], 1);
    }
}

// scan + dinv fused; grid = 2 (one block per encoder).
__global__ __launch_bounds__(1024) void scan2_kernel(const int* __restrict__ deg_all,
                                                     int* __restrict__ rp_all,
                                                     int* __restrict__ cur_all,
                                                     float* __restrict__ dinv_all, int n) {
    int enc = blockIdx.x;
    const int* deg = deg_all + (size_t)enc * n;
    int* row_ptr = rp_all + (size_t)enc * (n + 1);
    int* cursor = cur_all + (size_t)enc * n;
    float* dinv = dinv_all + (size_t)enc * n;

    __shared__ int sums[1024];
    int t = threadIdx.x;
    int chunk = (n + 1023) >> 10;
    int beg = t * chunk;
    int end = beg + chunk;
    if (beg > n) beg = n;
    if (end > n) end = n;
    int s = 0;
    for (int i = beg; i < end; ++i) s += deg[i];
    sums[t] = s;
    __syncthreads();
    for (int off = 1; off < 1024; off <<= 1) {
        int v = (t >= off) ? sums[t - off] : 0;
        __syncthreads();
        sums[t] += v;
        __syncthreads();
    }
    int run = sums[t] - s;
    for (int i = beg; i < end; ++i) {
        row_ptr[i] = run;
        cursor[i] = run;
        dinv[i] = rsqrtf((float)deg[i] + 1.0f);  // self-loop: deg+1
        run += deg[i];
    }
    if (t == 1023) row_ptr[n] = sums[1023];
}

// packed edge: {src, norm}; both encoders per dispatch
__global__ __launch_bounds__(256) void fill2_kernel(const int* __restrict__ ei_a,
                                                    const int* __restrict__ ei_b,
                                                    const float* __restrict__ dinv_all,
                                                    int* __restrict__ cur_all,
                                                    int2* __restrict__ ed_all,
                                                    int n, int e) {
    int i = blockIdx.x * 256 + threadIdx.x;
    if (i >= 2 * e) return;
    int enc = (i >= e) ? 1 : 0;
    int j = i - enc * e;
    const int* ei = enc ? ei_b : ei_a;
    const float* dinv = dinv_all + (size_t)enc * n;
    int* cursor = cur_all + (size_t)enc * n;
    int2* edges = ed_all + (size_t)enc * e;
    int s = ei[j], d = ei[e + j];
    int p = atomicAdd(&cursor[d], 1);
    int2 pr;
    pr.x = s;
    pr.y = __float_as_int(dinv[s] * dinv[d]);
    edges[p] = pr;
}

// ---------------- graph ranges from sorted batch (both encoders) ----------------

__global__ __launch_bounds__(256) void ranges2_kernel(const int* __restrict__ batch_a,
                                                      const int* __restrict__ batch_b,
                                                      int* __restrict__ startA,
                                                      int* __restrict__ startB,
                                                      int n, int g) {
    int i = blockIdx.x * 256 + threadIdx.x;
    if (i >= 2 * n) return;
    int enc = (i >= n) ? 1 : 0;
    int j = i - enc * n;
    const int* batch = enc ? batch_b : batch_a;
    int* start = enc ? startB : startA;
    int b = batch[j];
    if (j == 0) {
        for (int k = 0; k <= b; ++k) start[k] = 0;
    } else {
        int pb = batch[j - 1];
        for (int k = pb + 1; k <= b; ++k) start[k] = j;
    }
    if (j == n - 1) {
        for (int k = b + 1; k <= g; ++k) start[k] = n;
    }
}

// ---------------- W pre-transpose + bf16 hi/lo split (all 3 layers, one dispatch) ----------------

__global__ __launch_bounds__(256) void wsplit3_kernel(const float* __restrict__ W1,
                                                      const float* __restrict__ W2,
                                                      const float* __restrict__ W3,
                                                      unsigned short* __restrict__ hi_all,
                                                      unsigned short* __restrict__ lo_all) {
    __shared__ float tile[32][33];
    int layer = blockIdx.x >> 8;
    int b = blockIdx.x & 255;
    const float* W = (layer == 0) ? W1 : (layer == 1) ? W2 : W3;
    unsigned short* Wt_hi = hi_all + (size_t)layer * 512 * 512;
    unsigned short* Wt_lo = lo_all + (size_t)layer * 512 * 512;
    int k0 = (b & 15) * 32, n0 = (b >> 4) * 32;
    int t = threadIdx.x;
    int tc = t & 31, tr = t >> 5;
#pragma unroll
    for (int it = 0; it < 4; ++it)
        tile[tr + it * 8][tc] = W[(size_t)(k0 + tr + it * 8) * 512 + n0 + tc];
    __syncthreads();
#pragma unroll
    for (int it = 0; it < 4; ++it) {
        int n = tr + it * 8;
        float v = tile[tc][n];
        unsigned short hi = f2bf(v);
        unsigned short lo = f2bf(v - bf2f(hi));
        Wt_hi[(size_t)(n0 + n) * 512 + k0 + tc] = hi;
        Wt_lo[(size_t)(n0 + n) * 512 + k0 + tc] = lo;
    }
}

// ---------------- A bf16 hi/lo split (layer-1 input, both encoders) ----------------

__global__ __launch_bounds__(256) void asplit2_kernel(const float* __restrict__ x_a,
                                                      const float* __restrict__ x_b,
                                                      unsigned short* __restrict__ A_hi,
                                                      unsigned short* __restrict__ A_lo,
                                                      int n4) {
    int i = blockIdx.x * 256 + threadIdx.x;
    if (i >= 2 * n4) return;
    float4 v = (i < n4) ? ((const float4*)x_a)[i] : ((const float4*)x_b)[i - n4];
    ushort4 h, l;
    h.x = f2bf(v.x); l.x = f2bf(v.x - bf2f(h.x));
    h.y = f2bf(v.y); l.y = f2bf(v.y - bf2f(h.y));
    h.z = f2bf(v.z); l.z = f2bf(v.z - bf2f(h.z));
    h.w = f2bf(v.w); l.w = f2bf(v.w - bf2f(h.w));
    ((ushort4*)A_hi)[i] = h;
    ((ushort4*)A_lo)[i] = l;
}

// ---------------- split-bf16 MFMA GEMM: C16[M x 512] = A[M x 512] @ W[512 x 512] ----------------
// BM=64 BN=512 BK=32, 256 threads (4 waves side-by-side in N), per-wave 64x128 via
// 4x8 frags of 16x16x32. A read exactly once per GEMM; B (1 MB) stays L2-hot since all
// co-resident blocks sweep the same k0. Single-buffered LDS 72 KB -> 2 blocks/CU.

__global__ __launch_bounds__(256, 2) void gemm_mfma_kernel(const unsigned short* __restrict__ A_hi,
                                                           const unsigned short* __restrict__ A_lo,
                                                           const unsigned short* __restrict__ Bt_hi,
                                                           const unsigned short* __restrict__ Bt_lo,
                                                           __half* __restrict__ C, int M) {
    __shared__ unsigned short As_hi[64][32], As_lo[64][32];    // 4 KB each
    __shared__ unsigned short Bs_hi[512][32], Bs_lo[512][32];  // 32 KB each
    int row0 = blockIdx.x * 64;
    int t = threadIdx.x;
    int lane = t & 63, w = t >> 6;
    int r = lane & 15, g = lane >> 4;

    f32x4 acc[4][8] = {};

    int ar = t >> 2;          // 0..63: staged row
    int kq = (t & 3) * 8;     // k-quarter (elements)

    for (int k0 = 0; k0 < 512; k0 += 32) {
        // stage A (1 gload16/thread/plane) + B (8/plane); wave-uniform LDS base + lane*16
        gload16(A_hi + (size_t)(row0 + ar) * 512 + k0 + kq, &As_hi[w * 16][0]);
        gload16(A_lo + (size_t)(row0 + ar) * 512 + k0 + kq, &As_lo[w * 16][0]);
#pragma unroll
        for (int i = 0; i < 8; ++i) {
            int ldsrow = i * 64 + w * 16;
            gload16(Bt_hi + (size_t)(i * 64 + ar) * 512 + k0 + kq, &Bs_hi[ldsrow][0]);
            gload16(Bt_lo + (size_t)(i * 64 + ar) * 512 + k0 + kq, &Bs_lo[ldsrow][0]);
        }
        __syncthreads();  // drains vmcnt (global_load_lds) before reads

        bf16x8 ah[4], al[4];
#pragma unroll
        for (int m = 0; m < 4; ++m) {
            ah[m] = *(const bf16x8*)&As_hi[m * 16 + r][g * 8];
            al[m] = *(const bf16x8*)&As_lo[m * 16 + r][g * 8];
        }
#pragma unroll
        for (int n = 0; n < 8; ++n) {
            int cc = w * 128 + n * 16 + r;
            bf16x8 bh = *(const bf16x8*)&Bs_hi[cc][g * 8];
            bf16x8 bl = *(const bf16x8*)&Bs_lo[cc][g * 8];
#pragma unroll
            for (int m = 0; m < 4; ++m) {
                acc[m][n] = __builtin_amdgcn_mfma_f32_16x16x32_bf16(al[m], bh, acc[m][n], 0, 0, 0);
                acc[m][n] = __builtin_amdgcn_mfma_f32_16x16x32_bf16(ah[m], bl, acc[m][n], 0, 0, 0);
                acc[m][n] = __builtin_amdgcn_mfma_f32_16x16x32_bf16(ah[m], bh, acc[m][n], 0, 0, 0);
            }
        }
        __syncthreads();  // all waves done reading before next stage
    }

#pragma unroll
    for (int m = 0; m < 4; ++m)
#pragma unroll
        for (int j = 0; j < 4; ++j) {
            int rr = row0 + m * 16 + g * 4 + j;
            if (rr < M) {
#pragma unroll
                for (int n = 0; n < 8; ++n)
                    C[(size_t)rr * 512 + w * 128 + n * 16 + r] = __float2half(acc[m][n][j]);
            }
        }
}

// ---------------- fused aggregation (both encoders): one block per dst node ----------------
// agg[d] = sum_{e: dst=d} h16[src]*norm + h16[d]*dinv[d]^2 + b ; optional relu;
// output either bf16 hi/lo (next GEMM input) or fp32 (pool input).

template <bool RELU, bool SPLIT>
__global__ __launch_bounds__(256) void aggregate_kernel(const __half* __restrict__ H,  // [2N][512]
                                                        const int* __restrict__ rp_all,
                                                        const int2* __restrict__ ed_all,
                                                        const float* __restrict__ dinv_all,
                                                        const float* __restrict__ bias,
                                                        float* __restrict__ X,
                                                        unsigned short* __restrict__ Xhi,
                                                        unsigned short* __restrict__ Xlo,
                                                        int n, int e) {
    int dg = blockIdx.x;           // global row (concat)
    bool isB = dg >= n;
    int d = isB ? dg - n : dg;     // local node id
    const int* rp = rp_all + (isB ? (size_t)(n + 1) : 0);
    const int2* ed = ed_all + (isB ? (size_t)e : 0);
    const float* dv = dinv_all + (isB ? (size_t)n : 0);
    const __half* Hb = H + (isB ? (size_t)n * 512 : 0);

    int t = threadIdx.x;
    int beg = rp[d], end = rp[d + 1];
    float ax = 0.f, ay = 0.f;
    int j = beg;
    for (; j + 4 <= end; j += 4) {
        int2 e0 = ed[j], e1 = ed[j + 1], e2 = ed[j + 2], e3 = ed[j + 3];
        __half2 h0 = *(const __half2*)(Hb + (size_t)e0.x * 512 + t * 2);
        __half2 h1 = *(const __half2*)(Hb + (size_t)e1.x * 512 + t * 2);
        __half2 h2 = *(const __half2*)(Hb + (size_t)e2.x * 512 + t * 2);
        __half2 h3 = *(const __half2*)(Hb + (size_t)e3.x * 512 + t * 2);
        float2 f0 = __half22float2(h0), f1 = __half22float2(h1);
        float2 f2 = __half22float2(h2), f3 = __half22float2(h3);
        float w0 = __int_as_float(e0.y), w1 = __int_as_float(e1.y);
        float w2 = __int_as_float(e2.y), w3 = __int_as_float(e3.y);
        ax += w0 * f0.x + w1 * f1.x + w2 * f2.x + w3 * f3.x;
        ay += w0 * f0.y + w1 * f1.y + w2 * f2.y + w3 * f3.y;
    }
    for (; j < end; ++j) {
        int2 ej = ed[j];
        float w = __int_as_float(ej.y);
        float2 f = __half22float2(*(const __half2*)(Hb + (size_t)ej.x * 512 + t * 2));
        ax += w * f.x;
        ay += w * f.y;
    }
    float di = dv[d];
    float self = di * di;
    float2 hd = __half22float2(*(const __half2*)(Hb + (size_t)d * 512 + t * 2));
    float2 bb = *(const float2*)(bias + t * 2);
    float ox = ax + self * hd.x + bb.x;
    float oy = ay + self * hd.y + bb.y;
    if (RELU) {
        ox = fmaxf(ox, 0.f);
        oy = fmaxf(oy, 0.f);
    }
    if (SPLIT) {
        unsigned short hx = f2bf(ox), hy = f2bf(oy);
        unsigned short lx = f2bf(ox - bf2f(hx)), ly = f2bf(oy - bf2f(hy));
        *(ushort2*)(Xhi + (size_t)dg * 512 + t * 2) = make_ushort2(hx, hy);
        *(ushort2*)(Xlo + (size_t)dg * 512 + t * 2) = make_ushort2(lx, ly);
    } else {
        *(float2*)(X + (size_t)dg * 512 + t * 2) = make_float2(ox, oy);
    }
}

// ---------------- mean pool over sorted-batch ranges (both encoders) ----------------

__global__ __launch_bounds__(256) void pool_kernel(const float* __restrict__ X,  // [2N][512]
                                                   const int* __restrict__ startA,
                                                   const int* __restrict__ startB,
                                                   float* __restrict__ pool,  // [2G][512]
                                                   int n, int gcount) {
    int g = blockIdx.x;
    bool isB = g >= gcount;
    const int* st = isB ? startB : startA;
    int gl = isB ? g - gcount : g;
    const float* Xb = X + (isB ? (size_t)n * 512 : 0);
    int t = threadIdx.x;
    int s = st[gl], e = st[gl + 1];
    float ax = 0.f, ay = 0.f;
    int i = s;
    for (; i + 2 <= e; i += 2) {
        float2 v0 = *(const float2*)(Xb + (size_t)i * 512 + t * 2);
        float2 v1 = *(const float2*)(Xb + (size_t)(i + 1) * 512 + t * 2);
        ax += v0.x + v1.x;
        ay += v0.y + v1.y;
    }
    for (; i < e; ++i) {
        float2 v = *(const float2*)(Xb + (size_t)i * 512 + t * 2);
        ax += v.x;
        ay += v.y;
    }
    float cnt = fmaxf((float)(e - s), 1.0f);
    *(float2*)(pool + (size_t)g * 512 + t * 2) = make_float2(ax / cnt, ay / cnt);
}

// ---------------- pairwise distance ----------------

__global__ __launch_bounds__(64) void pdist_kernel(const float* __restrict__ pool,
                                                   float* __restrict__ out, int gcount) {
    int g = blockIdx.x;
    int t = threadIdx.x;
    const float* pa = pool + (size_t)g * 512;
    const float* pb = pool + (size_t)(gcount + g) * 512;
    float s = 0.f;
    for (int i = t; i < 512; i += 64) {
        float d = pa[i] - pb[i] + 1e-6f;
        s += d * d;
    }
#pragma unroll
    for (int off = 32; off; off >>= 1) s += __shfl_down(s, off);
    if (t == 0) out[g] = sqrtf(s);
}

// ---------------- launch ----------------

extern "C" void kernel_launch(void* const* d_in, const int* in_sizes, int n_in,
                              void* d_out, int out_size, void* d_ws, size_t ws_size,
                              hipStream_t stream) {
    const float* x_a = (const float*)d_in[0];
    const int* ei_a = (const int*)d_in[1];
    const int* batch_a = (const int*)d_in[2];
    const float* x_b = (const float*)d_in[3];
    const int* ei_b = (const int*)d_in[4];
    const int* batch_b = (const int*)d_in[5];
    const float* W1 = (const float*)d_in[6];
    const float* b1 = (const float*)d_in[7];
    const float* W2 = (const float*)d_in[8];
    const float* b2 = (const float*)d_in[9];
    const float* W3 = (const float*)d_in[10];
    const float* b3 = (const float*)d_in[11];
    float* out = (float*)d_out;

    const int N = in_sizes[0] / 512;
    const int E = in_sizes[1] / 2;
    const int G = out_size;
    const int M = 2 * N;                      // concat A|B
    const int Mpad = ((M + 127) / 128) * 128; // A-plane padded; tail rows read junk, never stored

    char* ws = (char*)d_ws;
    size_t off = 0;
    auto alloc = [&](size_t bytes) -> void* {
        void* p = ws + off;
        off = (off + bytes + 255) & ~(size_t)255;
        return p;
    };
    __half* bufH16 = (__half*)alloc((size_t)Mpad * 512 * 2);
    // a_hi | a_lo block; also aliased as fp32 X for layer-3 output (a_hi/a_lo dead by then)
    char* abblock = (char*)alloc((size_t)Mpad * 512 * 4);
    unsigned short* a_hi = (unsigned short*)abblock;
    unsigned short* a_lo = a_hi + (size_t)Mpad * 512;
    float* bufX = (float*)abblock;
    int* deg = (int*)alloc((size_t)2 * N * 4);        // [A | B]
    float* dinv = (float*)alloc((size_t)2 * N * 4);   // [A | B]
    int* rp = (int*)alloc((size_t)2 * (N + 1) * 4);   // [A | B]
    int* cur = (int*)alloc((size_t)2 * N * 4);        // [A | B]
    int2* ed = (int2*)alloc((size_t)2 * E * 8);       // [A | B]
    int* startA = (int*)alloc((size_t)(G + 1) * 4);
    int* startB = (int*)alloc((size_t)(G + 1) * 4);
    float* pool = (float*)alloc((size_t)2 * G * 512 * 4);
    unsigned short* wt_hi = (unsigned short*)alloc((size_t)3 * 512 * 512 * 2);
    unsigned short* wt_lo = (unsigned short*)alloc((size_t)3 * 512 * 512 * 2);

    const int gemm_grid = (M + 63) / 64;  // BM=64; M=40000 -> 625 exact
    const int n4 = N * 512 / 4;

    // weights: pre-transpose + split, all 3 layers (same every call; graph-capture safe)
    wsplit3_kernel<<<768, 256, 0, stream>>>(W1, W2, W3, wt_hi, wt_lo);

    // CSR build (A and B fused per dispatch), batch ranges
    hipMemsetAsync(deg, 0, (size_t)2 * N * 4, stream);
    deg2_kernel<<<(2 * E + 255) / 256, 256, 0, stream>>>(ei_a, ei_b, deg, N, E);
    scan2_kernel<<<2, 1024, 0, stream>>>(deg, rp, cur, dinv, N);
    fill2_kernel<<<(2 * E + 255) / 256, 256, 0, stream>>>(ei_a, ei_b, dinv, cur, ed, N, E);
    ranges2_kernel<<<(2 * N + 255) / 256, 256, 0, stream>>>(batch_a, batch_b, startA, startB, N, G);

    // layer-1 input: split x_a|x_b into concat bf16 hi/lo
    asplit2_kernel<<<(2 * n4 + 255) / 256, 256, 0, stream>>>(x_a, x_b, a_hi, a_lo, n4);

    // layer 1
    gemm_mfma_kernel<<<gemm_grid, 256, 0, stream>>>(a_hi, a_lo, wt_hi, wt_lo, bufH16, M);
    aggregate_kernel<true, true><<<M, 256, 0, stream>>>(bufH16, rp, ed, dinv, b1,
                                                        bufX, a_hi, a_lo, N, E);
    // layer 2
    gemm_mfma_kernel<<<gemm_grid, 256, 0, stream>>>(a_hi, a_lo, wt_hi + (size_t)512 * 512,
                                                    wt_lo + (size_t)512 * 512, bufH16, M);
    aggregate_kernel<true, true><<<M, 256, 0, stream>>>(bufH16, rp, ed, dinv, b2,
                                                        bufX, a_hi, a_lo, N, E);
    // layer 3 (fp32 out into the dead a_hi/a_lo block)
    gemm_mfma_kernel<<<gemm_grid, 256, 0, stream>>>(a_hi, a_lo, wt_hi + (size_t)2 * 512 * 512,
                                                    wt_lo + (size_t)2 * 512 * 512, bufH16, M);
    aggregate_kernel<false, false><<<M, 256, 0, stream>>>(bufH16, rp, ed, dinv, b3,
                                                          bufX, a_hi, a_lo, N, E);

    // pool + distance
    pool_kernel<<<2 * G, 256, 0, stream>>>(bufX, startA, startB, pool, N, G);
    pdist_kernel<<<G, 64, 0, stream>>>(pool, out, G);
}